// Round 3
// baseline (4662.773 us; speedup 1.0000x reference)
//
#include <hip/hip_runtime.h>
#include <hip/hip_bf16.h>
#include <math.h>

#define D_MODEL 512
#define NH 8
#define DH 64
#define NL 6
#define BB 4
#define SS 1024
#define ROWS (BB*SS)   // 4096
#define DFF 2048

// ---------------------------------------------------------------------------
// Embedding + positional encoding -> x (f32)
// ref: ang[s,i] = s * 10000^(-i/512); even i -> sin, odd i -> cos
// ---------------------------------------------------------------------------
__global__ __launch_bounds__(256) void embed_pe(const int* __restrict__ tok,
                                                const float* __restrict__ emb,
                                                float* __restrict__ x) {
    int row = blockIdx.x;           // 0..4095
    int s = row & (SS - 1);
    int t = tok[row];
    const float* e = emb + (size_t)t * D_MODEL;
    for (int i = threadIdx.x; i < D_MODEL; i += 256) {
        float freq = __expf(-9.210340371976184f * ((float)i / (float)D_MODEL)); // ln(10000)
        float ang = (float)s * freq;
        float pe = (i & 1) ? cosf(ang) : sinf(ang);
        x[(size_t)row * D_MODEL + i] = e[i] + pe;
    }
}

// ---------------------------------------------------------------------------
// Tiled f32 GEMM: C[M,N] = A[M,K] @ W[K,N] + bias, optional ReLU.
// 64x64 tile per 256-thread block, 4x4 per thread, BK=16. grid=(N/64, M/64)
// ---------------------------------------------------------------------------
__global__ __launch_bounds__(256) void gemm64(const float* __restrict__ A,
                                              const float* __restrict__ W,
                                              const float* __restrict__ bias,
                                              float* __restrict__ C,
                                              int N, int K, int relu) {
    __shared__ float sA[16][68];   // [kk][m]
    __shared__ float sB[16][68];   // [kk][n]

    const int tid = threadIdx.x;
    const int tm = tid >> 4;       // 0..15
    const int tn = tid & 15;       // 0..15
    const int row0 = blockIdx.y * 64;
    const int col0 = blockIdx.x * 64;

    float acc[4][4];
    #pragma unroll
    for (int i = 0; i < 4; i++)
        #pragma unroll
        for (int j = 0; j < 4; j++) acc[i][j] = 0.f;

    for (int k0 = 0; k0 < K; k0 += 16) {
        // A tile: 64 rows x 16 k
        #pragma unroll
        for (int it = 0; it < 4; it++) {
            int e = tid + it * 256;        // 0..1023
            int m = e >> 4;
            int kk = e & 15;
            sA[kk][m] = A[(size_t)(row0 + m) * K + k0 + kk];
        }
        // W tile: 16 k x 64 n (coalesced)
        #pragma unroll
        for (int it = 0; it < 4; it++) {
            int e = tid + it * 256;
            int kk = e >> 6;
            int n = e & 63;
            sB[kk][n] = W[(size_t)(k0 + kk) * N + col0 + n];
        }
        __syncthreads();

        #pragma unroll
        for (int kk = 0; kk < 16; kk++) {
            float4 a4 = *(const float4*)&sA[kk][tm * 4];
            float4 b4 = *(const float4*)&sB[kk][tn * 4];
            float a[4] = {a4.x, a4.y, a4.z, a4.w};
            float b[4] = {b4.x, b4.y, b4.z, b4.w};
            #pragma unroll
            for (int i = 0; i < 4; i++)
                #pragma unroll
                for (int j = 0; j < 4; j++) acc[i][j] += a[i] * b[j];
        }
        __syncthreads();
    }

    #pragma unroll
    for (int i = 0; i < 4; i++) {
        int r = row0 + tm * 4 + i;
        #pragma unroll
        for (int j = 0; j < 4; j++) {
            int c = col0 + tn * 4 + j;
            float v = acc[i][j] + bias[c];
            if (relu) v = fmaxf(v, 0.f);
            C[(size_t)r * N + c] = v;
        }
    }
}

// ---------------------------------------------------------------------------
// Flash attention. Q,K,V: [B,S,H*DH] f32 (GEMM outputs); O: [B,H,S,DH] f32.
// The natural [b][h][s][d] O layout, read flat as [4096,512], IS the
// reference's "buggy" reshape. Block = 4 waves; 64 q-rows per block; thread
// (r=lane, p=wave) owns q-row r (regs), scores for j in [16p,16p+16), and
// output dims [16p,16p+16). grid = (16 qtiles, NH, BB).
// ---------------------------------------------------------------------------
__global__ __launch_bounds__(256) void attn_kernel(const float* __restrict__ Q,
                                                   const float* __restrict__ Kb,
                                                   const float* __restrict__ Vb,
                                                   float* __restrict__ Ob) {
    __shared__ float sK[64][68];     // K tile; later reused as P[j][r]
    __shared__ float sV[64][68];
    __shared__ float sPmax[4][64];
    __shared__ float sPsum[4][64];

    const int r = threadIdx.x & 63;
    const int p = threadIdx.x >> 6;
    const int qt = blockIdx.x;
    const int h  = blockIdx.y;
    const int b  = blockIdx.z;

    const size_t qg = (size_t)(b * SS + qt * 64 + r) * D_MODEL + h * DH;
    float q[64];
    #pragma unroll
    for (int d4 = 0; d4 < 16; d4++) {
        float4 v = *(const float4*)(Q + qg + d4 * 4);
        q[d4 * 4 + 0] = v.x; q[d4 * 4 + 1] = v.y;
        q[d4 * 4 + 2] = v.z; q[d4 * 4 + 3] = v.w;
    }

    float O[16];
    #pragma unroll
    for (int i = 0; i < 16; i++) O[i] = 0.f;
    float m = -INFINITY, l = 0.f;

    for (int kt = 0; kt < 16; kt++) {
        // stage K,V tiles (64 rows x 64 dims each)
        #pragma unroll
        for (int it = 0; it < 4; it++) {
            int e = threadIdx.x + it * 256;  // 0..1023
            int j = e >> 4;
            int d4 = e & 15;
            size_t g = (size_t)(b * SS + kt * 64 + j) * D_MODEL + h * DH + d4 * 4;
            *(float4*)&sK[j][d4 * 4] = *(const float4*)(Kb + g);
            *(float4*)&sV[j][d4 * 4] = *(const float4*)(Vb + g);
        }
        __syncthreads();

        // s_j = (q . K_j) / 8 for this thread's 16 j's
        float s[16];
        #pragma unroll
        for (int jj = 0; jj < 16; jj++) s[jj] = 0.f;
        #pragma unroll
        for (int d4 = 0; d4 < 16; d4++) {
            float4 qv = *(const float4*)&q[d4 * 4];
            #pragma unroll
            for (int jj = 0; jj < 16; jj++) {
                float4 kv = *(const float4*)&sK[p * 16 + jj][d4 * 4];
                s[jj] += qv.x * kv.x + qv.y * kv.y + qv.z * kv.z + qv.w * kv.w;
            }
        }
        float pm = -INFINITY;
        #pragma unroll
        for (int jj = 0; jj < 16; jj++) { s[jj] *= 0.125f; pm = fmaxf(pm, s[jj]); }
        sPmax[p][r] = pm;
        __syncthreads();   // score reads of sK done; row maxima published

        float mt = fmaxf(fmaxf(sPmax[0][r], sPmax[1][r]),
                         fmaxf(sPmax[2][r], sPmax[3][r]));
        float mnew = fmaxf(m, mt);
        float alpha = __expf(m - mnew);   // m=-inf on first tile -> 0
        float ps = 0.f;
        #pragma unroll
        for (int jj = 0; jj < 16; jj++) {
            float pv = __expf(s[jj] - mnew);
            sK[p * 16 + jj][r] = pv;       // P stored transposed: P[j][r]
            ps += pv;
        }
        sPsum[p][r] = ps;
        #pragma unroll
        for (int i = 0; i < 16; i++) O[i] *= alpha;
        l = l * alpha;
        m = mnew;
        __syncthreads();   // P writes visible

        l += sPsum[0][r] + sPsum[1][r] + sPsum[2][r] + sPsum[3][r];
        // O[d] += sum_j P[j][r] * V[j][d] over this thread's 16-dim slice
        #pragma unroll 8
        for (int j = 0; j < 64; j++) {
            float pj = sK[j][r];
            const float* vr = &sV[j][p * 16];
            float4 v0 = *(const float4*)(vr);
            float4 v1 = *(const float4*)(vr + 4);
            float4 v2 = *(const float4*)(vr + 8);
            float4 v3 = *(const float4*)(vr + 12);
            O[0]  += pj * v0.x; O[1]  += pj * v0.y; O[2]  += pj * v0.z; O[3]  += pj * v0.w;
            O[4]  += pj * v1.x; O[5]  += pj * v1.y; O[6]  += pj * v1.z; O[7]  += pj * v1.w;
            O[8]  += pj * v2.x; O[9]  += pj * v2.y; O[10] += pj * v2.z; O[11] += pj * v2.w;
            O[12] += pj * v3.x; O[13] += pj * v3.y; O[14] += pj * v3.z; O[15] += pj * v3.w;
        }
        __syncthreads();   // P reads done before next tile overwrites sK
    }

    float inv = 1.f / l;
    size_t orow = ((size_t)((b * NH + h) * SS + qt * 64 + r)) * DH + p * 16;
    #pragma unroll
    for (int i4 = 0; i4 < 4; i4++) {
        float4 v;
        v.x = O[i4 * 4 + 0] * inv; v.y = O[i4 * 4 + 1] * inv;
        v.z = O[i4 * 4 + 2] * inv; v.w = O[i4 * 4 + 3] * inv;
        *(float4*)(Ob + orow + i4 * 4) = v;
    }
}

// ---------------------------------------------------------------------------
// out = LayerNorm(x + delta) * g + b   (one block per row; out may alias x)
// ---------------------------------------------------------------------------
__global__ __launch_bounds__(256) void add_ln(const float* __restrict__ x,
                                              const float* __restrict__ delta,
                                              const float* __restrict__ g,
                                              const float* __restrict__ bparm,
                                              float* __restrict__ out) {
    __shared__ float red[2][4];
    int row = blockIdx.x;
    int t = threadIdx.x;
    const float* xr = x + (size_t)row * D_MODEL;
    const float* dr = delta + (size_t)row * D_MODEL;
    float v0 = xr[t] + dr[t];
    float v1 = xr[t + 256] + dr[t + 256];
    float s = v0 + v1;
    float ss = v0 * v0 + v1 * v1;
    #pragma unroll
    for (int off = 1; off < 64; off <<= 1) {
        s  += __shfl_xor(s, off);
        ss += __shfl_xor(ss, off);
    }
    int lane = t & 63, wid = t >> 6;
    if (lane == 0) { red[0][wid] = s; red[1][wid] = ss; }
    __syncthreads();
    s  = red[0][0] + red[0][1] + red[0][2] + red[0][3];
    ss = red[1][0] + red[1][1] + red[1][2] + red[1][3];
    float mean = s * (1.f / D_MODEL);
    float var = ss * (1.f / D_MODEL) - mean * mean;
    float rinv = rsqrtf(var + 1e-5f);
    float* orow = out + (size_t)row * D_MODEL;
    orow[t]       = (v0 - mean) * rinv * g[t]       + bparm[t];
    orow[t + 256] = (v1 - mean) * rinv * g[t + 256] + bparm[t + 256];
}

// ---------------------------------------------------------------------------
extern "C" void kernel_launch(void* const* d_in, const int* in_sizes, int n_in,
                              void* d_out, int out_size, void* d_ws, size_t ws_size,
                              hipStream_t stream) {
    const int* tokens = (const int*)d_in[0];
    const float* emb = (const float*)d_in[1];
    const float* Wq = (const float*)d_in[2];  const float* bq = (const float*)d_in[3];
    const float* Wk = (const float*)d_in[4];  const float* bk = (const float*)d_in[5];
    const float* Wv = (const float*)d_in[6];  const float* bv = (const float*)d_in[7];
    const float* Wo = (const float*)d_in[8];  const float* bo = (const float*)d_in[9];
    const float* W1 = (const float*)d_in[10]; const float* b1 = (const float*)d_in[11];
    const float* W2 = (const float*)d_in[12]; const float* b2 = (const float*)d_in[13];
    const float* lng = (const float*)d_in[14]; const float* lnb = (const float*)d_in[15];

    const size_t M1 = 1024 * 1024;
    float* ws  = (float*)d_ws;
    float* x   = ws;               // 2M floats
    float* qb  = ws + 2 * M1;      // 2M
    float* kb  = ws + 4 * M1;      // 2M
    float* vb  = ws + 6 * M1;      // 2M
    float* ab  = ws + 8 * M1;      // 2M
    float* tmp = ws + 10 * M1;     // 2M
    float* mid = qb;               // 8M floats, reuses q/k/v/attn (dead by FFN)
    // total: 12M floats = 48 MB

    embed_pe<<<ROWS, 256, 0, stream>>>(tokens, emb, x);

    for (int l = 0; l < NL; l++) {
        const float* wq = Wq + (size_t)l * D_MODEL * D_MODEL;
        const float* wk = Wk + (size_t)l * D_MODEL * D_MODEL;
        const float* wv = Wv + (size_t)l * D_MODEL * D_MODEL;
        const float* wo = Wo + (size_t)l * D_MODEL * D_MODEL;
        const float* w1 = W1 + (size_t)l * D_MODEL * DFF;
        const float* w2 = W2 + (size_t)l * DFF * D_MODEL;

        gemm64<<<dim3(8, 64), 256, 0, stream>>>(x, wq, bq + l * D_MODEL, qb, D_MODEL, D_MODEL, 0);
        gemm64<<<dim3(8, 64), 256, 0, stream>>>(x, wk, bk + l * D_MODEL, kb, D_MODEL, D_MODEL, 0);
        gemm64<<<dim3(8, 64), 256, 0, stream>>>(x, wv, bv + l * D_MODEL, vb, D_MODEL, D_MODEL, 0);

        attn_kernel<<<dim3(16, NH, BB), 256, 0, stream>>>(qb, kb, vb, ab);

        gemm64<<<dim3(8, 64), 256, 0, stream>>>(ab, wo, bo + l * D_MODEL, tmp, D_MODEL, D_MODEL, 0);
        add_ln<<<ROWS, 256, 0, stream>>>(x, tmp, lng + l * D_MODEL, lnb + l * D_MODEL, x);

        gemm64<<<dim3(32, 64), 256, 0, stream>>>(x, w1, b1 + l * DFF, mid, DFF, D_MODEL, 1);
        gemm64<<<dim3(8, 64), 256, 0, stream>>>(mid, w2, b2 + l * D_MODEL, tmp, D_MODEL, DFF, 0);
        // final LN of the last layer writes straight to d_out (f32)
        float* lnout = (l == NL - 1) ? (float*)d_out : x;
        add_ln<<<ROWS, 256, 0, stream>>>(x, tmp, lng + l * D_MODEL, lnb + l * D_MODEL, lnout);
    }
}

// Round 4
// 2661.559 us; speedup vs baseline: 1.7519x; 1.7519x over previous
//
#include <hip/hip_runtime.h>
#include <hip/hip_bf16.h>
#include <math.h>

typedef unsigned short ushort_t;
typedef __attribute__((ext_vector_type(8))) short bfrag_t;   // 8 bf16 = 4 VGPRs
typedef __attribute__((ext_vector_type(4))) float facc_t;    // 4 f32 acc

#define D_MODEL 512
#define NH 8
#define DH 64
#define NL 6
#define BB 4
#define SS 1024
#define ROWS (BB*SS)   // 4096
#define DFF 2048

__device__ inline float bf2f(ushort_t u) { return __uint_as_float(((unsigned)u) << 16); }
__device__ inline ushort_t f2bf(float f) {
    __hip_bfloat16 h = __float2bfloat16(f);
    return *(ushort_t*)&h;
}
__device__ inline unsigned pack2(float a, float b) {
    return ((unsigned)f2bf(a)) | (((unsigned)f2bf(b)) << 16);
}
__device__ inline void unpack8(uint4 u, float* dst) {
    dst[0] = __uint_as_float(u.x << 16); dst[1] = __uint_as_float(u.x & 0xffff0000u);
    dst[2] = __uint_as_float(u.y << 16); dst[3] = __uint_as_float(u.y & 0xffff0000u);
    dst[4] = __uint_as_float(u.z << 16); dst[5] = __uint_as_float(u.z & 0xffff0000u);
    dst[6] = __uint_as_float(u.w << 16); dst[7] = __uint_as_float(u.w & 0xffff0000u);
}
__device__ inline void gload_lds16(const void* g, void* l) {
    __builtin_amdgcn_global_load_lds((const __attribute__((address_space(1))) unsigned int*)g,
                                     (__attribute__((address_space(3))) unsigned int*)l, 16, 0, 0);
}

// ---------------------------------------------------------------------------
// Embedding + positional encoding -> x (f32) and xbf (bf16)
// ---------------------------------------------------------------------------
__global__ __launch_bounds__(256) void embed_pe(const int* __restrict__ tok,
                                                const float* __restrict__ emb,
                                                float* __restrict__ x,
                                                ushort_t* __restrict__ xbf) {
    int row = blockIdx.x;
    int s = row & (SS - 1);
    int t = tok[row];
    const float* e = emb + (size_t)t * D_MODEL;
    for (int i = threadIdx.x; i < D_MODEL; i += 256) {
        float freq = __expf(-9.210340371976184f * ((float)i / (float)D_MODEL));
        float ang = (float)s * freq;
        float pe = (i & 1) ? cosf(ang) : sinf(ang);
        float v = e[i] + pe;
        x[(size_t)row * D_MODEL + i] = v;
        xbf[(size_t)row * D_MODEL + i] = f2bf(v);
    }
}

// ---------------------------------------------------------------------------
// Per-layer weight prep: cast f32 -> bf16 and transpose [K][N] -> [N][K].
// z = 0..2: Wq/Wk/Wv -> wlay rows [z*512, z*512+512) of the fused [1536][512]
// z = 3: Wo [512][512]; z = 4: W1 [512][2048] -> [2048][512];
// z = 5: W2 [2048][512] -> [512][2048].  grid (64,64,6); extra tiles early-out.
// ---------------------------------------------------------------------------
__global__ __launch_bounds__(256) void prep_weights(const float* __restrict__ Wq,
                                                    const float* __restrict__ Wk,
                                                    const float* __restrict__ Wv,
                                                    const float* __restrict__ Wo,
                                                    const float* __restrict__ W1,
                                                    const float* __restrict__ W2,
                                                    int layer, ushort_t* __restrict__ wlay) {
    __shared__ float tile[32][33];
    int z = blockIdx.z;
    const float* src; ushort_t* dst; int K, N;
    size_t o512 = (size_t)layer * 512 * 512;
    size_t o1M  = (size_t)layer * 512 * 2048;
    switch (z) {
        case 0: src = Wq + o512; dst = wlay;               K = 512;  N = 512;  break;
        case 1: src = Wk + o512; dst = wlay + 262144;      K = 512;  N = 512;  break;
        case 2: src = Wv + o512; dst = wlay + 524288;      K = 512;  N = 512;  break;
        case 3: src = Wo + o512; dst = wlay + 786432;      K = 512;  N = 512;  break;
        case 4: src = W1 + o1M;  dst = wlay + 1048576;     K = 512;  N = 2048; break;
        default:src = W2 + o1M;  dst = wlay + 2097152;     K = 2048; N = 512;  break;
    }
    int n0 = blockIdx.x * 32, k0 = blockIdx.y * 32;
    if (n0 >= N || k0 >= K) return;
    int tx = threadIdx.x & 31, ty = threadIdx.x >> 5;   // 8 rows/pass
    #pragma unroll
    for (int i = 0; i < 4; i++)
        tile[ty + i * 8][tx] = src[(size_t)(k0 + ty + i * 8) * N + n0 + tx];
    __syncthreads();
    #pragma unroll
    for (int i = 0; i < 4; i++)
        dst[(size_t)(n0 + ty + i * 8) * K + k0 + tx] = f2bf(tile[tx][ty + i * 8]);
}

// ---------------------------------------------------------------------------
// Concatenate qkv biases per layer: bqkv[l][1536] = [bq | bk | bv]
// ---------------------------------------------------------------------------
__global__ __launch_bounds__(256) void concat_bias(const float* __restrict__ bq,
                                                   const float* __restrict__ bk,
                                                   const float* __restrict__ bv,
                                                   float* __restrict__ bqkv) {
    int l = blockIdx.x;
    for (int i = threadIdx.x; i < 1536; i += 256) {
        float v = (i < 512) ? bq[l * 512 + i]
                : (i < 1024) ? bk[l * 512 + i - 512]
                : bv[l * 512 + i - 1024];
        bqkv[l * 1536 + i] = v;
    }
}

// ---------------------------------------------------------------------------
// MFMA bf16 GEMM: C[M,N] = A[M,K](bf16) @ Bt[N,K](bf16)^T + bias(f32).
// 128x128 tile / 256 threads (4 waves, 2x2), BK=64, mfma_f32_16x16x32_bf16.
// XOR-swizzled LDS (granule p = q ^ (row&7)) -> conflict-free ds_read_b128,
// staged with global_load_lds width 16. Outputs: f32 (Cf) and/or bf16 (Cb).
// grid = (N/128, M/128). M,N mult of 128; K mult of 64.
// ---------------------------------------------------------------------------
__global__ __launch_bounds__(256) void gemm_mfma(const ushort_t* __restrict__ A,
                                                 const ushort_t* __restrict__ Bt,
                                                 const float* __restrict__ bias,
                                                 float* __restrict__ Cf,
                                                 ushort_t* __restrict__ Cb,
                                                 int N, int K, int relu) {
    __shared__ ushort_t lA[128 * 64];
    __shared__ ushort_t lB[128 * 64];

    const int tid = threadIdx.x;
    const int w = tid >> 6, lane = tid & 63;
    const int wr = w & 1, wc = w >> 1;
    const int lane16 = lane & 15, quad = lane >> 4;
    const int row0 = blockIdx.y * 128, col0 = blockIdx.x * 128;

    facc_t acc[4][4];
    #pragma unroll
    for (int i = 0; i < 4; i++)
        #pragma unroll
        for (int j = 0; j < 4; j++)
            acc[i][j] = (facc_t){0.f, 0.f, 0.f, 0.f};

    for (int k0 = 0; k0 < K; k0 += 64) {
        __syncthreads();
        // stage: wave w covers tile rows w*32..w*32+31 (1024 granules of 16B)
        #pragma unroll
        for (int i = 0; i < 4; i++) {
            int g = w * 256 + i * 64 + lane;
            int r = g >> 3, p = g & 7;
            int q = p ^ (r & 7);
            gload_lds16(A + (size_t)(row0 + r) * K + k0 + q * 8, lA + (size_t)g * 8);
            gload_lds16(Bt + (size_t)(col0 + r) * K + k0 + q * 8, lB + (size_t)g * 8);
        }
        __syncthreads();

        #pragma unroll
        for (int kk = 0; kk < 2; kk++) {
            bfrag_t af[4], bfg[4];
            #pragma unroll
            for (int t = 0; t < 4; t++) {
                int m = wr * 64 + t * 16 + lane16;
                int q = kk * 4 + quad;
                af[t] = *(const bfrag_t*)(lA + ((size_t)m * 8 + (q ^ (m & 7))) * 8);
                int n = wc * 64 + t * 16 + lane16;
                bfg[t] = *(const bfrag_t*)(lB + ((size_t)n * 8 + (q ^ (n & 7))) * 8);
            }
            #pragma unroll
            for (int ti = 0; ti < 4; ti++)
                #pragma unroll
                for (int tj = 0; tj < 4; tj++)
                    acc[ti][tj] = __builtin_amdgcn_mfma_f32_16x16x32_bf16(
                        af[ti], bfg[tj], acc[ti][tj], 0, 0, 0);
        }
    }

    float bv_[4];
    #pragma unroll
    for (int tj = 0; tj < 4; tj++)
        bv_[tj] = bias[col0 + wc * 64 + tj * 16 + lane16];

    #pragma unroll
    for (int ti = 0; ti < 4; ti++) {
        int grow_base = row0 + wr * 64 + ti * 16 + quad * 4;
        #pragma unroll
        for (int tj = 0; tj < 4; tj++) {
            int gcol = col0 + wc * 64 + tj * 16 + lane16;
            #pragma unroll
            for (int rr = 0; rr < 4; rr++) {
                float v = acc[ti][tj][rr] + bv_[tj];
                if (relu) v = fmaxf(v, 0.f);
                size_t idx = (size_t)(grow_base + rr) * N + gcol;
                if (Cf) Cf[idx] = v;
                if (Cb) Cb[idx] = f2bf(v);
            }
        }
    }
}

// ---------------------------------------------------------------------------
// Flash attention. qkv: [4096][1536] bf16 (Q|K|V fused); ab: [B,H,S,DH] bf16
// (flat == reference's buggy reshape). f32 math in LDS/regs, unchanged from
// round 3 except bf16 load/store. grid = (16 qtiles, NH, BB), 256 threads.
// ---------------------------------------------------------------------------
__global__ __launch_bounds__(256) void attn_kernel(const ushort_t* __restrict__ qkv,
                                                   ushort_t* __restrict__ ab) {
    __shared__ float sK[64][68];     // K tile; later reused as P[j][r]
    __shared__ float sV[64][68];
    __shared__ float sPmax[4][64];
    __shared__ float sPsum[4][64];

    const int r = threadIdx.x & 63;
    const int p = threadIdx.x >> 6;
    const int qt = blockIdx.x;
    const int h  = blockIdx.y;
    const int b  = blockIdx.z;

    const ushort_t* Qp = qkv + (size_t)(b * SS + qt * 64 + r) * 1536 + h * DH;
    float q[64];
    #pragma unroll
    for (int d8 = 0; d8 < 8; d8++) {
        uint4 u = *(const uint4*)(Qp + d8 * 8);
        unpack8(u, &q[d8 * 8]);
    }

    float O[16];
    #pragma unroll
    for (int i = 0; i < 16; i++) O[i] = 0.f;
    float m = -INFINITY, l = 0.f;

    for (int kt = 0; kt < 16; kt++) {
        #pragma unroll
        for (int it = 0; it < 2; it++) {
            int e = threadIdx.x + it * 256;  // 0..511
            int j = e >> 3;
            int c = e & 7;
            size_t base = (size_t)(b * SS + kt * 64 + j) * 1536 + h * DH + c * 8;
            uint4 uk = *(const uint4*)(qkv + base + 512);
            uint4 uv = *(const uint4*)(qkv + base + 1024);
            unpack8(uk, &sK[j][c * 8]);
            unpack8(uv, &sV[j][c * 8]);
        }
        __syncthreads();

        float s[16];
        #pragma unroll
        for (int jj = 0; jj < 16; jj++) s[jj] = 0.f;
        #pragma unroll
        for (int d4 = 0; d4 < 16; d4++) {
            float4 qv = *(const float4*)&q[d4 * 4];
            #pragma unroll
            for (int jj = 0; jj < 16; jj++) {
                float4 kv = *(const float4*)&sK[p * 16 + jj][d4 * 4];
                s[jj] += qv.x * kv.x + qv.y * kv.y + qv.z * kv.z + qv.w * kv.w;
            }
        }
        float pm = -INFINITY;
        #pragma unroll
        for (int jj = 0; jj < 16; jj++) { s[jj] *= 0.125f; pm = fmaxf(pm, s[jj]); }
        sPmax[p][r] = pm;
        __syncthreads();

        float mt = fmaxf(fmaxf(sPmax[0][r], sPmax[1][r]),
                         fmaxf(sPmax[2][r], sPmax[3][r]));
        float mnew = fmaxf(m, mt);
        float alpha = __expf(m - mnew);
        float ps = 0.f;
        #pragma unroll
        for (int jj = 0; jj < 16; jj++) {
            float pv = __expf(s[jj] - mnew);
            sK[p * 16 + jj][r] = pv;
            ps += pv;
        }
        sPsum[p][r] = ps;
        #pragma unroll
        for (int i = 0; i < 16; i++) O[i] *= alpha;
        l = l * alpha;
        m = mnew;
        __syncthreads();

        l += sPsum[0][r] + sPsum[1][r] + sPsum[2][r] + sPsum[3][r];
        #pragma unroll 8
        for (int j = 0; j < 64; j++) {
            float pj = sK[j][r];
            const float* vr = &sV[j][p * 16];
            float4 v0 = *(const float4*)(vr);
            float4 v1 = *(const float4*)(vr + 4);
            float4 v2 = *(const float4*)(vr + 8);
            float4 v3 = *(const float4*)(vr + 12);
            O[0]  += pj * v0.x; O[1]  += pj * v0.y; O[2]  += pj * v0.z; O[3]  += pj * v0.w;
            O[4]  += pj * v1.x; O[5]  += pj * v1.y; O[6]  += pj * v1.z; O[7]  += pj * v1.w;
            O[8]  += pj * v2.x; O[9]  += pj * v2.y; O[10] += pj * v2.z; O[11] += pj * v2.w;
            O[12] += pj * v3.x; O[13] += pj * v3.y; O[14] += pj * v3.z; O[15] += pj * v3.w;
        }
        __syncthreads();
    }

    float inv = 1.f / l;
    size_t orow = ((size_t)((b * NH + h) * SS + qt * 64 + r)) * DH + p * 16;
    #pragma unroll
    for (int i = 0; i < 8; i++) {
        unsigned u = pack2(O[2 * i] * inv, O[2 * i + 1] * inv);
        *(unsigned*)(ab + orow + 2 * i) = u;
    }
}

// ---------------------------------------------------------------------------
// LayerNorm(x + delta) * g + b -> outf (f32) and outb (bf16)
// ---------------------------------------------------------------------------
__global__ __launch_bounds__(256) void add_ln(const float* __restrict__ x,
                                              const float* __restrict__ delta,
                                              const float* __restrict__ g,
                                              const float* __restrict__ bparm,
                                              float* __restrict__ outf,
                                              ushort_t* __restrict__ outb) {
    __shared__ float red[2][4];
    int row = blockIdx.x;
    int t = threadIdx.x;
    const float* xr = x + (size_t)row * D_MODEL;
    const float* dr = delta + (size_t)row * D_MODEL;
    float v0 = xr[t] + dr[t];
    float v1 = xr[t + 256] + dr[t + 256];
    float s = v0 + v1;
    float ss = v0 * v0 + v1 * v1;
    #pragma unroll
    for (int off = 1; off < 64; off <<= 1) {
        s  += __shfl_xor(s, off);
        ss += __shfl_xor(ss, off);
    }
    int lane = t & 63, wid = t >> 6;
    if (lane == 0) { red[0][wid] = s; red[1][wid] = ss; }
    __syncthreads();
    s  = red[0][0] + red[0][1] + red[0][2] + red[0][3];
    ss = red[1][0] + red[1][1] + red[1][2] + red[1][3];
    float mean = s * (1.f / D_MODEL);
    float var = ss * (1.f / D_MODEL) - mean * mean;
    float rinv = rsqrtf(var + 1e-5f);
    float o0 = (v0 - mean) * rinv * g[t]       + bparm[t];
    float o1 = (v1 - mean) * rinv * g[t + 256] + bparm[t + 256];
    float* orow = outf + (size_t)row * D_MODEL;
    orow[t] = o0; orow[t + 256] = o1;
    ushort_t* brow = outb + (size_t)row * D_MODEL;
    brow[t] = f2bf(o0); brow[t + 256] = f2bf(o1);
}

// ---------------------------------------------------------------------------
extern "C" void kernel_launch(void* const* d_in, const int* in_sizes, int n_in,
                              void* d_out, int out_size, void* d_ws, size_t ws_size,
                              hipStream_t stream) {
    const int* tokens = (const int*)d_in[0];
    const float* emb = (const float*)d_in[1];
    const float* Wq = (const float*)d_in[2];  const float* bq = (const float*)d_in[3];
    const float* Wk = (const float*)d_in[4];  const float* bk = (const float*)d_in[5];
    const float* Wv = (const float*)d_in[6];  const float* bv = (const float*)d_in[7];
    const float* Wo = (const float*)d_in[8];  const float* bo = (const float*)d_in[9];
    const float* W1 = (const float*)d_in[10]; const float* b1 = (const float*)d_in[11];
    const float* W2 = (const float*)d_in[12]; const float* b2 = (const float*)d_in[13];
    const float* lng = (const float*)d_in[14]; const float* lnb = (const float*)d_in[15];

    // ws layout (bytes) — total 44,077,056 < proven-working 48 MB
    char* base = (char*)d_ws;
    ushort_t* wlay = (ushort_t*)(base);                 //  6,291,456  rotating Wt
    float*    bqkv = (float*)   (base + 6291456);       //     36,864
    float*    x    = (float*)   (base + 6328320);       //  8,388,608
    ushort_t* xbf  = (ushort_t*)(base + 14716928);      //  4,194,304
    float*    tmp  = (float*)   (base + 18911232);      //  8,388,608
    ushort_t* qkv  = (ushort_t*)(base + 27299840);      // 12,582,912
    ushort_t* ab   = (ushort_t*)(base + 39882752);      //  4,194,304
    ushort_t* mid  = qkv;  // [4096][2048] bf16 = 16 MB, aliases qkv+ab (dead)

    ushort_t* wqkv_t = wlay;             // [1536][512]
    ushort_t* wo_t   = wlay + 786432;    // [512][512]
    ushort_t* w1_t   = wlay + 1048576;   // [2048][512]
    ushort_t* w2_t   = wlay + 2097152;   // [512][2048]

    concat_bias<<<NL, 256, 0, stream>>>(bq, bk, bv, bqkv);
    embed_pe<<<ROWS, 256, 0, stream>>>(tokens, emb, x, xbf);

    for (int l = 0; l < NL; l++) {
        prep_weights<<<dim3(64, 64, 6), 256, 0, stream>>>(Wq, Wk, Wv, Wo, W1, W2, l, wlay);

        // fused QKV: [4096,512] @ [512,1536] -> qkv bf16
        gemm_mfma<<<dim3(12, 32), 256, 0, stream>>>(xbf, wqkv_t, bqkv + l * 1536,
                                                    nullptr, qkv, 1536, 512, 0);
        attn_kernel<<<dim3(16, NH, BB), 256, 0, stream>>>(qkv, ab);

        gemm_mfma<<<dim3(4, 32), 256, 0, stream>>>(ab, wo_t, bo + l * D_MODEL,
                                                   tmp, nullptr, 512, 512, 0);
        add_ln<<<ROWS, 256, 0, stream>>>(x, tmp, lng + l * D_MODEL, lnb + l * D_MODEL,
                                         x, xbf);

        gemm_mfma<<<dim3(16, 32), 256, 0, stream>>>(xbf, w1_t, b1 + l * DFF,
                                                    nullptr, mid, 2048, 512, 1);
        gemm_mfma<<<dim3(4, 32), 256, 0, stream>>>(mid, w2_t, b2 + l * D_MODEL,
                                                   tmp, nullptr, 512, 2048, 0);
        float* lnout = (l == NL - 1) ? (float*)d_out : x;
        add_ln<<<ROWS, 256, 0, stream>>>(x, tmp, lng + l * D_MODEL, lnb + l * D_MODEL,
                                         lnout, xbf);
    }
}

// Round 5
// 1081.629 us; speedup vs baseline: 4.3109x; 2.4607x over previous
//
#include <hip/hip_runtime.h>
#include <hip/hip_bf16.h>
#include <math.h>

typedef unsigned short ushort_t;
typedef __attribute__((ext_vector_type(8))) short bfrag_t;   // 8 bf16 = 4 VGPRs
typedef __attribute__((ext_vector_type(4))) float facc_t;    // 4 f32 acc

#define D_MODEL 512
#define NH 8
#define DH 64
#define NL 6
#define BB 4
#define SS 1024
#define ROWS (BB*SS)   // 4096
#define DFF 2048

__device__ inline ushort_t f2bf(float f) {
    __hip_bfloat16 h = __float2bfloat16(f);
    return *(ushort_t*)&h;
}
__device__ inline void gload_lds16(const void* g, void* l) {
    __builtin_amdgcn_global_load_lds((const __attribute__((address_space(1))) unsigned int*)g,
                                     (__attribute__((address_space(3))) unsigned int*)l, 16, 0, 0);
}

// ---------------------------------------------------------------------------
// Embedding + positional encoding -> x (f32) and xbf (bf16)
// ---------------------------------------------------------------------------
__global__ __launch_bounds__(256) void embed_pe(const int* __restrict__ tok,
                                                const float* __restrict__ emb,
                                                float* __restrict__ x,
                                                ushort_t* __restrict__ xbf) {
    int row = blockIdx.x;
    int s = row & (SS - 1);
    int t = tok[row];
    const float* e = emb + (size_t)t * D_MODEL;
    for (int i = threadIdx.x; i < D_MODEL; i += 256) {
        float freq = __expf(-9.210340371976184f * ((float)i / (float)D_MODEL));
        float ang = (float)s * freq;
        float pe = (i & 1) ? cosf(ang) : sinf(ang);
        float v = e[i] + pe;
        x[(size_t)row * D_MODEL + i] = v;
        xbf[(size_t)row * D_MODEL + i] = f2bf(v);
    }
}

// ---------------------------------------------------------------------------
// Per-layer weight prep: cast f32 -> bf16 and transpose [K][N] -> [N][K].
// ---------------------------------------------------------------------------
__global__ __launch_bounds__(256) void prep_weights(const float* __restrict__ Wq,
                                                    const float* __restrict__ Wk,
                                                    const float* __restrict__ Wv,
                                                    const float* __restrict__ Wo,
                                                    const float* __restrict__ W1,
                                                    const float* __restrict__ W2,
                                                    int layer, ushort_t* __restrict__ wlay) {
    __shared__ float tile[32][33];
    int z = blockIdx.z;
    const float* src; ushort_t* dst; int K, N;
    size_t o512 = (size_t)layer * 512 * 512;
    size_t o1M  = (size_t)layer * 512 * 2048;
    switch (z) {
        case 0: src = Wq + o512; dst = wlay;               K = 512;  N = 512;  break;
        case 1: src = Wk + o512; dst = wlay + 262144;      K = 512;  N = 512;  break;
        case 2: src = Wv + o512; dst = wlay + 524288;      K = 512;  N = 512;  break;
        case 3: src = Wo + o512; dst = wlay + 786432;      K = 512;  N = 512;  break;
        case 4: src = W1 + o1M;  dst = wlay + 1048576;     K = 512;  N = 2048; break;
        default:src = W2 + o1M;  dst = wlay + 2097152;     K = 2048; N = 512;  break;
    }
    int n0 = blockIdx.x * 32, k0 = blockIdx.y * 32;
    if (n0 >= N || k0 >= K) return;
    int tx = threadIdx.x & 31, ty = threadIdx.x >> 5;
    #pragma unroll
    for (int i = 0; i < 4; i++)
        tile[ty + i * 8][tx] = src[(size_t)(k0 + ty + i * 8) * N + n0 + tx];
    __syncthreads();
    #pragma unroll
    for (int i = 0; i < 4; i++)
        dst[(size_t)(n0 + ty + i * 8) * K + k0 + tx] = f2bf(tile[tx][ty + i * 8]);
}

// ---------------------------------------------------------------------------
// Concatenate qkv biases per layer: bqkv[l][1536] = [bq | bk | bv]
// ---------------------------------------------------------------------------
__global__ __launch_bounds__(256) void concat_bias(const float* __restrict__ bq,
                                                   const float* __restrict__ bk,
                                                   const float* __restrict__ bv,
                                                   float* __restrict__ bqkv) {
    int l = blockIdx.x;
    for (int i = threadIdx.x; i < 1536; i += 256) {
        float v = (i < 512) ? bq[l * 512 + i]
                : (i < 1024) ? bk[l * 512 + i - 512]
                : bv[l * 512 + i - 1024];
        bqkv[l * 1536 + i] = v;
    }
}

// ---------------------------------------------------------------------------
// MFMA bf16 GEMM: C[M,N] = A[M,K](bf16) @ Bt[N,K](bf16)^T + bias(f32).
// 128x128 tile / 256 threads, BK=64, XOR-swizzled LDS, global_load_lds w16.
// ---------------------------------------------------------------------------
__global__ __launch_bounds__(256) void gemm_mfma(const ushort_t* __restrict__ A,
                                                 const ushort_t* __restrict__ Bt,
                                                 const float* __restrict__ bias,
                                                 float* __restrict__ Cf,
                                                 ushort_t* __restrict__ Cb,
                                                 int N, int K, int relu) {
    __shared__ ushort_t lA[128 * 64];
    __shared__ ushort_t lB[128 * 64];

    const int tid = threadIdx.x;
    const int w = tid >> 6, lane = tid & 63;
    const int wr = w & 1, wc = w >> 1;
    const int lane16 = lane & 15, quad = lane >> 4;
    const int row0 = blockIdx.y * 128, col0 = blockIdx.x * 128;

    facc_t acc[4][4];
    #pragma unroll
    for (int i = 0; i < 4; i++)
        #pragma unroll
        for (int j = 0; j < 4; j++)
            acc[i][j] = (facc_t){0.f, 0.f, 0.f, 0.f};

    for (int k0 = 0; k0 < K; k0 += 64) {
        __syncthreads();
        #pragma unroll
        for (int i = 0; i < 4; i++) {
            int g = w * 256 + i * 64 + lane;
            int r = g >> 3, p = g & 7;
            int q = p ^ (r & 7);
            gload_lds16(A + (size_t)(row0 + r) * K + k0 + q * 8, lA + (size_t)g * 8);
            gload_lds16(Bt + (size_t)(col0 + r) * K + k0 + q * 8, lB + (size_t)g * 8);
        }
        __syncthreads();

        #pragma unroll
        for (int kk = 0; kk < 2; kk++) {
            bfrag_t af[4], bfg[4];
            #pragma unroll
            for (int t = 0; t < 4; t++) {
                int m = wr * 64 + t * 16 + lane16;
                int q = kk * 4 + quad;
                af[t] = *(const bfrag_t*)(lA + ((size_t)m * 8 + (q ^ (m & 7))) * 8);
                int n = wc * 64 + t * 16 + lane16;
                bfg[t] = *(const bfrag_t*)(lB + ((size_t)n * 8 + (q ^ (n & 7))) * 8);
            }
            #pragma unroll
            for (int ti = 0; ti < 4; ti++)
                #pragma unroll
                for (int tj = 0; tj < 4; tj++)
                    acc[ti][tj] = __builtin_amdgcn_mfma_f32_16x16x32_bf16(
                        af[ti], bfg[tj], acc[ti][tj], 0, 0, 0);
        }
    }

    float bv_[4];
    #pragma unroll
    for (int tj = 0; tj < 4; tj++)
        bv_[tj] = bias[col0 + wc * 64 + tj * 16 + lane16];

    #pragma unroll
    for (int ti = 0; ti < 4; ti++) {
        int grow_base = row0 + wr * 64 + ti * 16 + quad * 4;
        #pragma unroll
        for (int tj = 0; tj < 4; tj++) {
            int gcol = col0 + wc * 64 + tj * 16 + lane16;
            #pragma unroll
            for (int rr = 0; rr < 4; rr++) {
                float v = acc[ti][tj][rr] + bv_[tj];
                if (relu) v = fmaxf(v, 0.f);
                size_t idx = (size_t)(grow_base + rr) * N + gcol;
                if (Cf) Cf[idx] = v;
                if (Cb) Cb[idx] = f2bf(v);
            }
        }
    }
}

// ---------------------------------------------------------------------------
// MFMA flash attention. qkv: [4096][1536] bf16 (Q|K|V). ab: [B,H,S,DH] bf16.
// 4 waves/block; wave owns a 16-row Q strip. Per 64-key tile:
//   QK^T: 8 MFMAs (A=Q frags in regs, B=K from swizzled LDS)
//   online softmax in C-layout regs (row = quad*4+r, owned by lane16-group)
//   P: f32->bf16, C-layout -> A-layout via wave-private LDS round-trip
//   PV: 8 MFMAs (B = V^T staged transposed+swizzled)
// grid = (16 qtiles, NH, BB).
// ---------------------------------------------------------------------------
__global__ __launch_bounds__(256) void attn_mfma(const ushort_t* __restrict__ qkv,
                                                 ushort_t* __restrict__ ab) {
    __shared__ __align__(16) ushort_t lK[4096];   // [64 key][64 dh] swizzled
    __shared__ __align__(16) ushort_t lVT[4096];  // [64 dh][64 key] swizzled
    __shared__ __align__(16) ushort_t lP[4096];   // 4 x [16 q][64 key] swizzled

    const int tid = threadIdx.x;
    const int w = tid >> 6, lane = tid & 63;
    const int lane16 = lane & 15, quad = lane >> 4;
    const int qt = blockIdx.x, h = blockIdx.y, b = blockIdx.z;

    // Q A-fragments for this wave's 16 rows (held in regs all loop)
    const ushort_t* Qrow = qkv + (size_t)(b * SS + qt * 64 + w * 16 + lane16) * 1536 + h * 64;
    bfrag_t qa[2];
    #pragma unroll
    for (int ks = 0; ks < 2; ks++)
        qa[ks] = *(const bfrag_t*)(Qrow + ks * 32 + quad * 8);

    facc_t O[4];
    #pragma unroll
    for (int t = 0; t < 4; t++) O[t] = (facc_t){0.f, 0.f, 0.f, 0.f};
    float mrow[4] = {-INFINITY, -INFINITY, -INFINITY, -INFINITY};
    float lrow[4] = {0.f, 0.f, 0.f, 0.f};

    const int vkey = tid & 63;   // VT staging assignment
    const int vdg  = tid >> 6;

    for (int kt = 0; kt < 16; kt++) {
        // K tile -> LDS via async DMA, XOR-swizzled on source column
        #pragma unroll
        for (int i = 0; i < 2; i++) {
            int g = w * 128 + i * 64 + lane;
            int r = g >> 3, p = g & 7;
            int q = p ^ (r & 7);
            gload_lds16(qkv + (size_t)(b * SS + kt * 64 + r) * 1536 + h * 64 + 512 + q * 8,
                        lK + (size_t)g * 8);
        }
        // V tile -> LDS transposed ([dh][key]), swizzled
        {
            const ushort_t* vsrc = qkv + (size_t)(b * SS + kt * 64 + vkey) * 1536
                                   + h * 64 + 1024 + vdg * 16;
            uint4 u0 = *(const uint4*)(vsrc);
            uint4 u1 = *(const uint4*)(vsrc + 8);
            ushort_t vs[16];
            *(uint4*)(vs) = u0; *(uint4*)(vs + 8) = u1;
            int k8 = vkey >> 3, j = vkey & 7;
            #pragma unroll
            for (int e = 0; e < 16; e++) {
                int n = vdg * 16 + e;
                lVT[(size_t)(n * 8 + (k8 ^ (n & 7))) * 8 + j] = vs[e];
            }
        }
        __syncthreads();

        // QK^T
        facc_t sf[4];
        #pragma unroll
        for (int t = 0; t < 4; t++) sf[t] = (facc_t){0.f, 0.f, 0.f, 0.f};
        #pragma unroll
        for (int ks = 0; ks < 2; ks++) {
            #pragma unroll
            for (int t = 0; t < 4; t++) {
                int row = t * 16 + lane16;
                int q = ks * 4 + quad;
                bfrag_t kf = *(const bfrag_t*)(lK + ((size_t)row * 8 + (q ^ (row & 7))) * 8);
                sf[t] = __builtin_amdgcn_mfma_f32_16x16x32_bf16(qa[ks], kf, sf[t], 0, 0, 0);
            }
        }

        // online softmax; scores scaled by 1/8
        float mt_[4], al[4], ps[4];
        #pragma unroll
        for (int r = 0; r < 4; r++)
            mt_[r] = fmaxf(fmaxf(sf[0][r], sf[1][r]), fmaxf(sf[2][r], sf[3][r])) * 0.125f;
        #pragma unroll
        for (int off = 1; off < 16; off <<= 1)
            #pragma unroll
            for (int r = 0; r < 4; r++)
                mt_[r] = fmaxf(mt_[r], __shfl_xor(mt_[r], off));
        #pragma unroll
        for (int r = 0; r < 4; r++) {
            float mn = fmaxf(mrow[r], mt_[r]);
            al[r] = __expf(mrow[r] - mn);   // first tile: exp(-inf)=0
            mrow[r] = mn;
            ps[r] = 0.f;
        }

        ushort_t* Pw = lP + w * 1024;
        #pragma unroll
        for (int t = 0; t < 4; t++) {
            int k8 = t * 2 + (lane16 >> 3);
            int j = lane16 & 7;
            #pragma unroll
            for (int r = 0; r < 4; r++) {
                float p = __expf(sf[t][r] * 0.125f - mrow[r]);
                ps[r] += p;
                int row = quad * 4 + r;
                Pw[(size_t)(row * 8 + (k8 ^ (row & 7))) * 8 + j] = f2bf(p);
            }
        }
        #pragma unroll
        for (int off = 1; off < 16; off <<= 1)
            #pragma unroll
            for (int r = 0; r < 4; r++)
                ps[r] += __shfl_xor(ps[r], off);
        #pragma unroll
        for (int r = 0; r < 4; r++)
            lrow[r] = lrow[r] * al[r] + ps[r];
        #pragma unroll
        for (int t = 0; t < 4; t++)
            #pragma unroll
            for (int r = 0; r < 4; r++)
                O[t][r] *= al[r];

        // PV (P wave-private: no barrier needed before reads)
        #pragma unroll
        for (int ks = 0; ks < 2; ks++) {
            int q = ks * 4 + quad;
            bfrag_t pf = *(const bfrag_t*)(Pw + ((size_t)lane16 * 8 + (q ^ (lane16 & 7))) * 8);
            #pragma unroll
            for (int t = 0; t < 4; t++) {
                int n = t * 16 + lane16;
                bfrag_t vf = *(const bfrag_t*)(lVT + ((size_t)n * 8 + (q ^ (n & 7))) * 8);
                O[t] = __builtin_amdgcn_mfma_f32_16x16x32_bf16(pf, vf, O[t], 0, 0, 0);
            }
        }
        __syncthreads();   // lK/lVT reads done before next tile restages
    }

    // epilogue: normalize, store bf16 to ab[b][h][s][dh] (flat == ref reshape)
    size_t obase = ((size_t)((b * NH + h) * SS) + qt * 64 + w * 16 + quad * 4) * DH;
    #pragma unroll
    for (int r = 0; r < 4; r++) {
        float inv = 1.f / lrow[r];
        #pragma unroll
        for (int t = 0; t < 4; t++)
            ab[obase + (size_t)r * DH + t * 16 + lane16] = f2bf(O[t][r] * inv);
    }
}

// ---------------------------------------------------------------------------
// LayerNorm(x + delta) * g + b -> outf (f32) and outb (bf16)
// ---------------------------------------------------------------------------
__global__ __launch_bounds__(256) void add_ln(const float* __restrict__ x,
                                              const float* __restrict__ delta,
                                              const float* __restrict__ g,
                                              const float* __restrict__ bparm,
                                              float* __restrict__ outf,
                                              ushort_t* __restrict__ outb) {
    __shared__ float red[2][4];
    int row = blockIdx.x;
    int t = threadIdx.x;
    const float* xr = x + (size_t)row * D_MODEL;
    const float* dr = delta + (size_t)row * D_MODEL;
    float v0 = xr[t] + dr[t];
    float v1 = xr[t + 256] + dr[t + 256];
    float s = v0 + v1;
    float ss = v0 * v0 + v1 * v1;
    #pragma unroll
    for (int off = 1; off < 64; off <<= 1) {
        s  += __shfl_xor(s, off);
        ss += __shfl_xor(ss, off);
    }
    int lane = t & 63, wid = t >> 6;
    if (lane == 0) { red[0][wid] = s; red[1][wid] = ss; }
    __syncthreads();
    s  = red[0][0] + red[0][1] + red[0][2] + red[0][3];
    ss = red[1][0] + red[1][1] + red[1][2] + red[1][3];
    float mean = s * (1.f / D_MODEL);
    float var = ss * (1.f / D_MODEL) - mean * mean;
    float rinv = rsqrtf(var + 1e-5f);
    float o0 = (v0 - mean) * rinv * g[t]       + bparm[t];
    float o1 = (v1 - mean) * rinv * g[t + 256] + bparm[t + 256];
    float* orow = outf + (size_t)row * D_MODEL;
    orow[t] = o0; orow[t + 256] = o1;
    ushort_t* brow = outb + (size_t)row * D_MODEL;
    brow[t] = f2bf(o0); brow[t + 256] = f2bf(o1);
}

// ---------------------------------------------------------------------------
extern "C" void kernel_launch(void* const* d_in, const int* in_sizes, int n_in,
                              void* d_out, int out_size, void* d_ws, size_t ws_size,
                              hipStream_t stream) {
    const int* tokens = (const int*)d_in[0];
    const float* emb = (const float*)d_in[1];
    const float* Wq = (const float*)d_in[2];  const float* bq = (const float*)d_in[3];
    const float* Wk = (const float*)d_in[4];  const float* bk = (const float*)d_in[5];
    const float* Wv = (const float*)d_in[6];  const float* bv = (const float*)d_in[7];
    const float* Wo = (const float*)d_in[8];  const float* bo = (const float*)d_in[9];
    const float* W1 = (const float*)d_in[10]; const float* b1 = (const float*)d_in[11];
    const float* W2 = (const float*)d_in[12]; const float* b2 = (const float*)d_in[13];
    const float* lng = (const float*)d_in[14]; const float* lnb = (const float*)d_in[15];

    // ws layout (bytes) — total 44,077,056
    char* base = (char*)d_ws;
    ushort_t* wlay = (ushort_t*)(base);                 //  6,291,456  rotating Wt
    float*    bqkv = (float*)   (base + 6291456);       //     36,864
    float*    x    = (float*)   (base + 6328320);       //  8,388,608
    ushort_t* xbf  = (ushort_t*)(base + 14716928);      //  4,194,304
    float*    tmp  = (float*)   (base + 18911232);      //  8,388,608
    ushort_t* qkv  = (ushort_t*)(base + 27299840);      // 12,582,912
    ushort_t* ab   = (ushort_t*)(base + 39882752);      //  4,194,304
    ushort_t* mid  = qkv;  // [4096][2048] bf16, aliases qkv+ab (dead by FFN)

    ushort_t* wqkv_t = wlay;             // [1536][512]
    ushort_t* wo_t   = wlay + 786432;    // [512][512]
    ushort_t* w1_t   = wlay + 1048576;   // [2048][512]
    ushort_t* w2_t   = wlay + 2097152;   // [512][2048]

    concat_bias<<<NL, 256, 0, stream>>>(bq, bk, bv, bqkv);
    embed_pe<<<ROWS, 256, 0, stream>>>(tokens, emb, x, xbf);

    for (int l = 0; l < NL; l++) {
        prep_weights<<<dim3(64, 64, 6), 256, 0, stream>>>(Wq, Wk, Wv, Wo, W1, W2, l, wlay);

        gemm_mfma<<<dim3(12, 32), 256, 0, stream>>>(xbf, wqkv_t, bqkv + l * 1536,
                                                    nullptr, qkv, 1536, 512, 0);
        attn_mfma<<<dim3(16, NH, BB), 256, 0, stream>>>(qkv, ab);

        gemm_mfma<<<dim3(4, 32), 256, 0, stream>>>(ab, wo_t, bo + l * D_MODEL,
                                                   tmp, nullptr, 512, 512, 0);
        add_ln<<<ROWS, 256, 0, stream>>>(x, tmp, lng + l * D_MODEL, lnb + l * D_MODEL,
                                         x, xbf);

        gemm_mfma<<<dim3(16, 32), 256, 0, stream>>>(xbf, w1_t, b1 + l * DFF,
                                                    nullptr, mid, 2048, 512, 1);
        gemm_mfma<<<dim3(4, 32), 256, 0, stream>>>(mid, w2_t, b2 + l * D_MODEL,
                                                   tmp, nullptr, 512, 2048, 0);
        float* lnout = (l == NL - 1) ? (float*)d_out : x;
        add_ln<<<ROWS, 256, 0, stream>>>(x, tmp, lng + l * D_MODEL, lnb + l * D_MODEL,
                                         lnout, xbf);
    }
}

// Round 6
// 969.307 us; speedup vs baseline: 4.8104x; 1.1159x over previous
//
#include <hip/hip_runtime.h>
#include <hip/hip_bf16.h>
#include <math.h>

typedef unsigned short ushort_t;
typedef __attribute__((ext_vector_type(8))) short bfrag_t;   // 8 bf16 = 4 VGPRs
typedef __attribute__((ext_vector_type(4))) float facc_t;    // 4 f32 acc

#define D_MODEL 512
#define NH 8
#define DH 64
#define NL 6
#define BB 4
#define SS 1024
#define ROWS (BB*SS)   // 4096
#define DFF 2048

__device__ inline ushort_t f2bf(float f) {
    __hip_bfloat16 h = __float2bfloat16(f);
    return *(ushort_t*)&h;
}
__device__ inline void gload_lds16(const void* g, void* l) {
    __builtin_amdgcn_global_load_lds((const __attribute__((address_space(1))) unsigned int*)g,
                                     (__attribute__((address_space(3))) unsigned int*)l, 16, 0, 0);
}

// ---------------------------------------------------------------------------
// Embedding + positional encoding -> x (f32) and xbf (bf16)
// ---------------------------------------------------------------------------
__global__ __launch_bounds__(256) void embed_pe(const int* __restrict__ tok,
                                                const float* __restrict__ emb,
                                                float* __restrict__ x,
                                                ushort_t* __restrict__ xbf) {
    int row = blockIdx.x;
    int s = row & (SS - 1);
    int t = tok[row];
    const float* e = emb + (size_t)t * D_MODEL;
    for (int i = threadIdx.x; i < D_MODEL; i += 256) {
        float freq = __expf(-9.210340371976184f * ((float)i / (float)D_MODEL));
        float ang = (float)s * freq;
        float pe = (i & 1) ? cosf(ang) : sinf(ang);
        float v = e[i] + pe;
        x[(size_t)row * D_MODEL + i] = v;
        xbf[(size_t)row * D_MODEL + i] = f2bf(v);
    }
}

// ---------------------------------------------------------------------------
// Per-layer weight prep: cast f32 -> bf16 and transpose [K][N] -> [N][K].
// ---------------------------------------------------------------------------
__global__ __launch_bounds__(256) void prep_weights(const float* __restrict__ Wq,
                                                    const float* __restrict__ Wk,
                                                    const float* __restrict__ Wv,
                                                    const float* __restrict__ Wo,
                                                    const float* __restrict__ W1,
                                                    const float* __restrict__ W2,
                                                    int layer, ushort_t* __restrict__ wlay) {
    __shared__ float tile[32][33];
    int z = blockIdx.z;
    const float* src; ushort_t* dst; int K, N;
    size_t o512 = (size_t)layer * 512 * 512;
    size_t o1M  = (size_t)layer * 512 * 2048;
    switch (z) {
        case 0: src = Wq + o512; dst = wlay;               K = 512;  N = 512;  break;
        case 1: src = Wk + o512; dst = wlay + 262144;      K = 512;  N = 512;  break;
        case 2: src = Wv + o512; dst = wlay + 524288;      K = 512;  N = 512;  break;
        case 3: src = Wo + o512; dst = wlay + 786432;      K = 512;  N = 512;  break;
        case 4: src = W1 + o1M;  dst = wlay + 1048576;     K = 512;  N = 2048; break;
        default:src = W2 + o1M;  dst = wlay + 2097152;     K = 2048; N = 512;  break;
    }
    int n0 = blockIdx.x * 32, k0 = blockIdx.y * 32;
    if (n0 >= N || k0 >= K) return;
    int tx = threadIdx.x & 31, ty = threadIdx.x >> 5;
    #pragma unroll
    for (int i = 0; i < 4; i++)
        tile[ty + i * 8][tx] = src[(size_t)(k0 + ty + i * 8) * N + n0 + tx];
    __syncthreads();
    #pragma unroll
    for (int i = 0; i < 4; i++)
        dst[(size_t)(n0 + ty + i * 8) * K + k0 + tx] = f2bf(tile[tx][ty + i * 8]);
}

// ---------------------------------------------------------------------------
// Concatenate qkv biases per layer: bqkv[l][1536] = [bq | bk | bv]
// ---------------------------------------------------------------------------
__global__ __launch_bounds__(256) void concat_bias(const float* __restrict__ bq,
                                                   const float* __restrict__ bk,
                                                   const float* __restrict__ bv,
                                                   float* __restrict__ bqkv) {
    int l = blockIdx.x;
    for (int i = threadIdx.x; i < 1536; i += 256) {
        float v = (i < 512) ? bq[l * 512 + i]
                : (i < 1024) ? bk[l * 512 + i - 512]
                : bv[l * 512 + i - 1024];
        bqkv[l * 1536 + i] = v;
    }
}

// ---------------------------------------------------------------------------
// MFMA bf16 GEMM, 128x128 tile / 256 threads, BK=64. For large-N outputs.
// ---------------------------------------------------------------------------
__global__ __launch_bounds__(256) void gemm_mfma(const ushort_t* __restrict__ A,
                                                 const ushort_t* __restrict__ Bt,
                                                 const float* __restrict__ bias,
                                                 float* __restrict__ Cf,
                                                 ushort_t* __restrict__ Cb,
                                                 int N, int K, int relu) {
    __shared__ ushort_t lA[128 * 64];
    __shared__ ushort_t lB[128 * 64];

    const int tid = threadIdx.x;
    const int w = tid >> 6, lane = tid & 63;
    const int wr = w & 1, wc = w >> 1;
    const int lane16 = lane & 15, quad = lane >> 4;
    const int row0 = blockIdx.y * 128, col0 = blockIdx.x * 128;

    facc_t acc[4][4];
    #pragma unroll
    for (int i = 0; i < 4; i++)
        #pragma unroll
        for (int j = 0; j < 4; j++)
            acc[i][j] = (facc_t){0.f, 0.f, 0.f, 0.f};

    for (int k0 = 0; k0 < K; k0 += 64) {
        __syncthreads();
        #pragma unroll
        for (int i = 0; i < 4; i++) {
            int g = w * 256 + i * 64 + lane;
            int r = g >> 3, p = g & 7;
            int q = p ^ (r & 7);
            gload_lds16(A + (size_t)(row0 + r) * K + k0 + q * 8, lA + (size_t)g * 8);
            gload_lds16(Bt + (size_t)(col0 + r) * K + k0 + q * 8, lB + (size_t)g * 8);
        }
        __syncthreads();

        #pragma unroll
        for (int kk = 0; kk < 2; kk++) {
            bfrag_t af[4], bfg[4];
            #pragma unroll
            for (int t = 0; t < 4; t++) {
                int m = wr * 64 + t * 16 + lane16;
                int q = kk * 4 + quad;
                af[t] = *(const bfrag_t*)(lA + ((size_t)m * 8 + (q ^ (m & 7))) * 8);
                int n = wc * 64 + t * 16 + lane16;
                bfg[t] = *(const bfrag_t*)(lB + ((size_t)n * 8 + (q ^ (n & 7))) * 8);
            }
            #pragma unroll
            for (int ti = 0; ti < 4; ti++)
                #pragma unroll
                for (int tj = 0; tj < 4; tj++)
                    acc[ti][tj] = __builtin_amdgcn_mfma_f32_16x16x32_bf16(
                        af[ti], bfg[tj], acc[ti][tj], 0, 0, 0);
        }
    }

    float bv_[4];
    #pragma unroll
    for (int tj = 0; tj < 4; tj++)
        bv_[tj] = bias[col0 + wc * 64 + tj * 16 + lane16];

    #pragma unroll
    for (int ti = 0; ti < 4; ti++) {
        int grow_base = row0 + wr * 64 + ti * 16 + quad * 4;
        #pragma unroll
        for (int tj = 0; tj < 4; tj++) {
            int gcol = col0 + wc * 64 + tj * 16 + lane16;
            #pragma unroll
            for (int rr = 0; rr < 4; rr++) {
                float v = acc[ti][tj][rr] + bv_[tj];
                if (relu) v = fmaxf(v, 0.f);
                size_t idx = (size_t)(grow_base + rr) * N + gcol;
                if (Cf) Cf[idx] = v;
                if (Cb) Cb[idx] = f2bf(v);
            }
        }
    }
}

// ---------------------------------------------------------------------------
// MFMA bf16 GEMM, 64x64 tile / 256 threads, BK=64. For N=512 outputs (Wo/W2):
// grid (N/64=8, M/64=64) = 512 blocks -> 2/CU vs 128-tile's 0.5/CU.
// Wave w covers 32x32 quadrant (wr=w&1 rows, wc=w>>1 cols), 2x2 frags.
// ---------------------------------------------------------------------------
__global__ __launch_bounds__(256) void gemm_mfma64(const ushort_t* __restrict__ A,
                                                   const ushort_t* __restrict__ Bt,
                                                   const float* __restrict__ bias,
                                                   float* __restrict__ Cf,
                                                   ushort_t* __restrict__ Cb,
                                                   int N, int K, int relu) {
    __shared__ ushort_t lA[64 * 64];
    __shared__ ushort_t lB[64 * 64];

    const int tid = threadIdx.x;
    const int w = tid >> 6, lane = tid & 63;
    const int wr = w & 1, wc = w >> 1;
    const int lane16 = lane & 15, quad = lane >> 4;
    const int row0 = blockIdx.y * 64, col0 = blockIdx.x * 64;

    facc_t acc[2][2];
    #pragma unroll
    for (int i = 0; i < 2; i++)
        #pragma unroll
        for (int j = 0; j < 2; j++)
            acc[i][j] = (facc_t){0.f, 0.f, 0.f, 0.f};

    for (int k0 = 0; k0 < K; k0 += 64) {
        __syncthreads();
        // A: 512 granules, B: 512 granules; 4 waves x 128
        #pragma unroll
        for (int i = 0; i < 2; i++) {
            int g = w * 128 + i * 64 + lane;
            int r = g >> 3, p = g & 7;
            int q = p ^ (r & 7);
            gload_lds16(A + (size_t)(row0 + r) * K + k0 + q * 8, lA + (size_t)g * 8);
            gload_lds16(Bt + (size_t)(col0 + r) * K + k0 + q * 8, lB + (size_t)g * 8);
        }
        __syncthreads();

        #pragma unroll
        for (int kk = 0; kk < 2; kk++) {
            bfrag_t af[2], bfg[2];
            #pragma unroll
            for (int t = 0; t < 2; t++) {
                int m = wr * 32 + t * 16 + lane16;
                int q = kk * 4 + quad;
                af[t] = *(const bfrag_t*)(lA + ((size_t)m * 8 + (q ^ (m & 7))) * 8);
                int n = wc * 32 + t * 16 + lane16;
                bfg[t] = *(const bfrag_t*)(lB + ((size_t)n * 8 + (q ^ (n & 7))) * 8);
            }
            #pragma unroll
            for (int ti = 0; ti < 2; ti++)
                #pragma unroll
                for (int tj = 0; tj < 2; tj++)
                    acc[ti][tj] = __builtin_amdgcn_mfma_f32_16x16x32_bf16(
                        af[ti], bfg[tj], acc[ti][tj], 0, 0, 0);
        }
    }

    float bv_[2];
    #pragma unroll
    for (int tj = 0; tj < 2; tj++)
        bv_[tj] = bias[col0 + wc * 32 + tj * 16 + lane16];

    #pragma unroll
    for (int ti = 0; ti < 2; ti++) {
        int grow_base = row0 + wr * 32 + ti * 16 + quad * 4;
        #pragma unroll
        for (int tj = 0; tj < 2; tj++) {
            int gcol = col0 + wc * 32 + tj * 16 + lane16;
            #pragma unroll
            for (int rr = 0; rr < 4; rr++) {
                float v = acc[ti][tj][rr] + bv_[tj];
                if (relu) v = fmaxf(v, 0.f);
                size_t idx = (size_t)(grow_base + rr) * N + gcol;
                if (Cf) Cf[idx] = v;
                if (Cb) Cb[idx] = f2bf(v);
            }
        }
    }
}

// ---------------------------------------------------------------------------
// MFMA flash attention. 128 threads = 2 waves; 32 q-rows/block; grid
// (32 qtiles, NH, BB) = 1024 blocks (4/CU, 16 waves/CU vs round-5's 8).
// Wave w owns 16-row Q strip. Per 64-key tile: QK^T (8 MFMA) -> online
// softmax in C-layout regs -> P via wave-private LDS -> PV (8 MFMA, V^T).
// ---------------------------------------------------------------------------
__global__ __launch_bounds__(128) void attn_mfma(const ushort_t* __restrict__ qkv,
                                                 ushort_t* __restrict__ ab) {
    __shared__ __align__(16) ushort_t lK[4096];   // [64 key][64 dh] swizzled
    __shared__ __align__(16) ushort_t lVT[4096];  // [64 dh][64 key] swizzled
    __shared__ __align__(16) ushort_t lP[2048];   // 2 x [16 q][64 key] swizzled

    const int tid = threadIdx.x;
    const int w = tid >> 6, lane = tid & 63;
    const int lane16 = lane & 15, quad = lane >> 4;
    const int qt = blockIdx.x, h = blockIdx.y, b = blockIdx.z;

    // Q A-fragments for this wave's 16 rows (regs for entire loop)
    const ushort_t* Qrow = qkv + (size_t)(b * SS + qt * 32 + w * 16 + lane16) * 1536 + h * 64;
    bfrag_t qa[2];
    #pragma unroll
    for (int ks = 0; ks < 2; ks++)
        qa[ks] = *(const bfrag_t*)(Qrow + ks * 32 + quad * 8);

    facc_t O[4];
    #pragma unroll
    for (int t = 0; t < 4; t++) O[t] = (facc_t){0.f, 0.f, 0.f, 0.f};
    float mrow[4] = {-INFINITY, -INFINITY, -INFINITY, -INFINITY};
    float lrow[4] = {0.f, 0.f, 0.f, 0.f};

    const int vkey = tid & 63;   // V^T staging: thread -> (key, dh half)
    const int vdg  = tid >> 6;   // 0 or 1 -> dh in [vdg*32, vdg*32+32)

    for (int kt = 0; kt < 16; kt++) {
        // K tile -> LDS via async DMA (swizzled): 512 granules / 128 thr
        #pragma unroll
        for (int i = 0; i < 4; i++) {
            int g = i * 128 + tid;
            int r = g >> 3, p = g & 7;
            int q = p ^ (r & 7);
            gload_lds16(qkv + (size_t)(b * SS + kt * 64 + r) * 1536 + h * 64 + 512 + q * 8,
                        lK + (size_t)g * 8);
        }
        // V tile -> LDS transposed ([dh][key]), swizzled: 32 dh per thread
        {
            const ushort_t* vsrc = qkv + (size_t)(b * SS + kt * 64 + vkey) * 1536
                                   + h * 64 + 1024 + vdg * 32;
            ushort_t vs[32];
            #pragma unroll
            for (int i4 = 0; i4 < 4; i4++)
                *(uint4*)(vs + i4 * 8) = *(const uint4*)(vsrc + i4 * 8);
            int k8 = vkey >> 3, j = vkey & 7;
            #pragma unroll
            for (int e = 0; e < 32; e++) {
                int n = vdg * 32 + e;
                lVT[(size_t)(n * 8 + (k8 ^ (n & 7))) * 8 + j] = vs[e];
            }
        }
        __syncthreads();

        // QK^T
        facc_t sf[4];
        #pragma unroll
        for (int t = 0; t < 4; t++) sf[t] = (facc_t){0.f, 0.f, 0.f, 0.f};
        #pragma unroll
        for (int ks = 0; ks < 2; ks++) {
            #pragma unroll
            for (int t = 0; t < 4; t++) {
                int row = t * 16 + lane16;
                int q = ks * 4 + quad;
                bfrag_t kf = *(const bfrag_t*)(lK + ((size_t)row * 8 + (q ^ (row & 7))) * 8);
                sf[t] = __builtin_amdgcn_mfma_f32_16x16x32_bf16(qa[ks], kf, sf[t], 0, 0, 0);
            }
        }

        // online softmax (scores scaled 1/8)
        float mt_[4], al[4], ps[4];
        #pragma unroll
        for (int r = 0; r < 4; r++)
            mt_[r] = fmaxf(fmaxf(sf[0][r], sf[1][r]), fmaxf(sf[2][r], sf[3][r])) * 0.125f;
        #pragma unroll
        for (int off = 1; off < 16; off <<= 1)
            #pragma unroll
            for (int r = 0; r < 4; r++)
                mt_[r] = fmaxf(mt_[r], __shfl_xor(mt_[r], off));
        #pragma unroll
        for (int r = 0; r < 4; r++) {
            float mn = fmaxf(mrow[r], mt_[r]);
            al[r] = __expf(mrow[r] - mn);   // first tile: exp(-inf)=0
            mrow[r] = mn;
            ps[r] = 0.f;
        }

        ushort_t* Pw = lP + w * 1024;
        #pragma unroll
        for (int t = 0; t < 4; t++) {
            int k8 = t * 2 + (lane16 >> 3);
            int j = lane16 & 7;
            #pragma unroll
            for (int r = 0; r < 4; r++) {
                float p = __expf(sf[t][r] * 0.125f - mrow[r]);
                ps[r] += p;
                int row = quad * 4 + r;
                Pw[(size_t)(row * 8 + (k8 ^ (row & 7))) * 8 + j] = f2bf(p);
            }
        }
        #pragma unroll
        for (int off = 1; off < 16; off <<= 1)
            #pragma unroll
            for (int r = 0; r < 4; r++)
                ps[r] += __shfl_xor(ps[r], off);
        #pragma unroll
        for (int r = 0; r < 4; r++)
            lrow[r] = lrow[r] * al[r] + ps[r];
        #pragma unroll
        for (int t = 0; t < 4; t++)
            #pragma unroll
            for (int r = 0; r < 4; r++)
                O[t][r] *= al[r];

        // PV (P wave-private: no barrier needed)
        #pragma unroll
        for (int ks = 0; ks < 2; ks++) {
            int q = ks * 4 + quad;
            bfrag_t pf = *(const bfrag_t*)(Pw + ((size_t)lane16 * 8 + (q ^ (lane16 & 7))) * 8);
            #pragma unroll
            for (int t = 0; t < 4; t++) {
                int n = t * 16 + lane16;
                bfrag_t vf = *(const bfrag_t*)(lVT + ((size_t)n * 8 + (q ^ (n & 7))) * 8);
                O[t] = __builtin_amdgcn_mfma_f32_16x16x32_bf16(pf, vf, O[t], 0, 0, 0);
            }
        }
        __syncthreads();   // lK/lVT reads done before next tile restages
    }

    // epilogue: normalize, store bf16 (flat [b][h][s][d] == ref reshape)
    size_t obase = ((size_t)((b * NH + h) * SS) + qt * 32 + w * 16 + quad * 4) * DH;
    #pragma unroll
    for (int r = 0; r < 4; r++) {
        float inv = 1.f / lrow[r];
        #pragma unroll
        for (int t = 0; t < 4; t++)
            ab[obase + (size_t)r * DH + t * 16 + lane16] = f2bf(O[t][r] * inv);
    }
}

// ---------------------------------------------------------------------------
// LayerNorm(x + delta) * g + b -> outf (f32) and outb (bf16)
// ---------------------------------------------------------------------------
__global__ __launch_bounds__(256) void add_ln(const float* __restrict__ x,
                                              const float* __restrict__ delta,
                                              const float* __restrict__ g,
                                              const float* __restrict__ bparm,
                                              float* __restrict__ outf,
                                              ushort_t* __restrict__ outb) {
    __shared__ float red[2][4];
    int row = blockIdx.x;
    int t = threadIdx.x;
    const float* xr = x + (size_t)row * D_MODEL;
    const float* dr = delta + (size_t)row * D_MODEL;
    float v0 = xr[t] + dr[t];
    float v1 = xr[t + 256] + dr[t + 256];
    float s = v0 + v1;
    float ss = v0 * v0 + v1 * v1;
    #pragma unroll
    for (int off = 1; off < 64; off <<= 1) {
        s  += __shfl_xor(s, off);
        ss += __shfl_xor(ss, off);
    }
    int lane = t & 63, wid = t >> 6;
    if (lane == 0) { red[0][wid] = s; red[1][wid] = ss; }
    __syncthreads();
    s  = red[0][0] + red[0][1] + red[0][2] + red[0][3];
    ss = red[1][0] + red[1][1] + red[1][2] + red[1][3];
    float mean = s * (1.f / D_MODEL);
    float var = ss * (1.f / D_MODEL) - mean * mean;
    float rinv = rsqrtf(var + 1e-5f);
    float o0 = (v0 - mean) * rinv * g[t]       + bparm[t];
    float o1 = (v1 - mean) * rinv * g[t + 256] + bparm[t + 256];
    float* orow = outf + (size_t)row * D_MODEL;
    orow[t] = o0; orow[t + 256] = o1;
    ushort_t* brow = outb + (size_t)row * D_MODEL;
    brow[t] = f2bf(o0); brow[t + 256] = f2bf(o1);
}

// ---------------------------------------------------------------------------
extern "C" void kernel_launch(void* const* d_in, const int* in_sizes, int n_in,
                              void* d_out, int out_size, void* d_ws, size_t ws_size,
                              hipStream_t stream) {
    const int* tokens = (const int*)d_in[0];
    const float* emb = (const float*)d_in[1];
    const float* Wq = (const float*)d_in[2];  const float* bq = (const float*)d_in[3];
    const float* Wk = (const float*)d_in[4];  const float* bk = (const float*)d_in[5];
    const float* Wv = (const float*)d_in[6];  const float* bv = (const float*)d_in[7];
    const float* Wo = (const float*)d_in[8];  const float* bo = (const float*)d_in[9];
    const float* W1 = (const float*)d_in[10]; const float* b1 = (const float*)d_in[11];
    const float* W2 = (const float*)d_in[12]; const float* b2 = (const float*)d_in[13];
    const float* lng = (const float*)d_in[14]; const float* lnb = (const float*)d_in[15];

    // ws layout (bytes) — total 44,077,056
    char* base = (char*)d_ws;
    ushort_t* wlay = (ushort_t*)(base);                 //  6,291,456  rotating Wt
    float*    bqkv = (float*)   (base + 6291456);       //     36,864
    float*    x    = (float*)   (base + 6328320);       //  8,388,608
    ushort_t* xbf  = (ushort_t*)(base + 14716928);      //  4,194,304
    float*    tmp  = (float*)   (base + 18911232);      //  8,388,608
    ushort_t* qkv  = (ushort_t*)(base + 27299840);      // 12,582,912
    ushort_t* ab   = (ushort_t*)(base + 39882752);      //  4,194,304
    ushort_t* mid  = qkv;  // [4096][2048] bf16, aliases qkv+ab (dead by FFN)

    ushort_t* wqkv_t = wlay;             // [1536][512]
    ushort_t* wo_t   = wlay + 786432;    // [512][512]
    ushort_t* w1_t   = wlay + 1048576;   // [2048][512]
    ushort_t* w2_t   = wlay + 2097152;   // [512][2048]

    concat_bias<<<NL, 256, 0, stream>>>(bq, bk, bv, bqkv);
    embed_pe<<<ROWS, 256, 0, stream>>>(tokens, emb, x, xbf);

    for (int l = 0; l < NL; l++) {
        prep_weights<<<dim3(64, 64, 6), 256, 0, stream>>>(Wq, Wk, Wv, Wo, W1, W2, l, wlay);

        gemm_mfma<<<dim3(12, 32), 256, 0, stream>>>(xbf, wqkv_t, bqkv + l * 1536,
                                                    nullptr, qkv, 1536, 512, 0);
        attn_mfma<<<dim3(32, NH, BB), 128, 0, stream>>>(qkv, ab);

        gemm_mfma64<<<dim3(8, 64), 256, 0, stream>>>(ab, wo_t, bo + l * D_MODEL,
                                                     tmp, nullptr, 512, 512, 0);
        add_ln<<<ROWS, 256, 0, stream>>>(x, tmp, lng + l * D_MODEL, lnb + l * D_MODEL,
                                         x, xbf);

        gemm_mfma<<<dim3(16, 32), 256, 0, stream>>>(xbf, w1_t, b1 + l * DFF,
                                                    nullptr, mid, 2048, 512, 1);
        gemm_mfma64<<<dim3(8, 64), 256, 0, stream>>>(mid, w2_t, b2 + l * D_MODEL,
                                                     tmp, nullptr, 512, 2048, 0);
        float* lnout = (l == NL - 1) ? (float*)d_out : x;
        add_ln<<<ROWS, 256, 0, stream>>>(x, tmp, lng + l * D_MODEL, lnb + l * D_MODEL,
                                         lnout, xbf);
    }
}